// Round 7
// baseline (841.677 us; speedup 1.0000x reference)
//
#include <hip/hip_runtime.h>
#include <math.h>

// Problem constants
#define BB   64
#define CIN  16
#define LL   8192
#define CO   32
#define TCO  64
constexpr int T0n = 128;   // frames for n=64
constexpr int T1n = 32;    // frames for n=256
constexpr int F0n = 33;
constexpr int F1n = 129;

typedef unsigned int   uint32;
typedef unsigned short u16;
typedef __attribute__((ext_vector_type(8))) _Float16 half8;  // 8 f16 (4 VGPRs)
typedef __attribute__((ext_vector_type(4))) float    f32x4;  // MFMA accumulator

// ---------------- STFT: real-input DFT, k<->n-k pairing, rotation recurrence ----
// p layout: [b][t][c][f] (float2 = re,im)
template<int N, int F, int TCH, int TFR>
__global__ __launch_bounds__(256)
void stft_kernel(const float* __restrict__ x, float2* __restrict__ p) {
    constexpr int NCH  = TFR / TCH;
    constexpr int SPAN = N * TCH;          // 512 for both configs
    static_assert(SPAN == 512, "span");
    __shared__ float  xs[SPAN];
    __shared__ float2 uv[TCH][N / 2];      // (u,v), k=1..N/2-1
    __shared__ float2 edge[TCH];           // (x[0], x[N/2])
    int bid   = blockIdx.x;
    int chunk = bid % NCH;
    int bc    = bid / NCH;                 // b*CIN + c
    const float* xrow = x + (size_t)bc * LL;
    int g0 = chunk * SPAN - N / 2;
    for (int i = threadIdx.x; i < SPAN; i += 256) {
        int gi = g0 + i; gi = gi < 0 ? -gi : gi;   // reflect (left edge only)
        xs[i] = xrow[gi];
    }
    __syncthreads();
    for (int i = threadIdx.x; i < TCH * (N / 2); i += 256) {
        int fl = i / (N / 2), k = i % (N / 2);
        float a = xs[fl * N + k];
        if (k == 0) {
            edge[fl] = make_float2(a, xs[fl * N + N / 2]);
        } else {
            float b2 = xs[fl * N + N - k];
            uv[fl][k] = make_float2(a + b2, a - b2);
        }
    }
    __syncthreads();
    int c = bc % CIN, b = bc / CIN;
    for (int j = threadIdx.x; j < TCH * F; j += 256) {
        int fl = j / F, f = j - fl * F;
        float2 e = edge[fl];
        float re = e.x + ((f & 1) ? -e.y : e.y);
        float im = 0.f;
        float s1, c1;
        sincosf(6.28318530717958647692f * (float)f / (float)N, &s1, &c1);
        float cc = c1, ss = s1;            // angle = 2*pi*f*k/N at k=1
        #pragma unroll 4
        for (int k = 1; k < N / 2; ++k) {
            float2 w = uv[fl][k];
            re = fmaf(w.x, cc, re);        // + u*cos
            im = fmaf(-w.y, ss, im);       // - v*sin
            float cn = fmaf(cc, c1, -ss * s1);
            ss = fmaf(cc, s1, ss * c1);
            cc = cn;
        }
        int t = chunk * TCH + fl;
        p[(((size_t)b * TFR + t) * CIN + c) * F + f] = make_float2(re, im);
    }
}

// ---------------- merge (attention over 4 sub-frames), in-place into p1 --------
__global__ __launch_bounds__(256)
void merge_kernel(const float2* __restrict__ p0, float2* __restrict__ p1,
                  const float* __restrict__ mkr, const float* __restrict__ mki,
                  const float* __restrict__ mbr, const float* __restrict__ mbi) {
    int idx = blockIdx.x * 256 + threadIdx.x;
    const int total = BB * T1n * CIN * F0n;
    if (idx >= total) return;
    int f0 = idx % F0n; int r1 = idx / F0n;
    int c  = r1 % CIN;  int r2 = r1 / CIN;
    int t1 = r2 % T1n;  int b  = r2 / T1n;
    float2 pm[4];
    #pragma unroll
    for (int r = 0; r < 4; ++r) {
        int t = t1 * 4 + r;
        pm[r] = p0[(((size_t)b * T0n + t) * CIN + c) * F0n + f0];
    }
    float mag[4], mx = -1e30f;
    #pragma unroll
    for (int s = 0; s < 4; ++s) {
        float atr = mbr[s], ati = mbi[s];
        #pragma unroll
        for (int r = 0; r < 4; ++r) {
            float kr = mkr[r * 4 + s], ki = mki[r * 4 + s];
            atr = fmaf(pm[r].x, kr, atr); atr = fmaf(-pm[r].y, ki, atr);
            ati = fmaf(pm[r].x, ki, ati); ati = fmaf(pm[r].y, kr, ati);
        }
        mag[s] = sqrtf(atr * atr + ati * ati);
        mx = fmaxf(mx, mag[s]);
    }
    float se = 0.f;
    #pragma unroll
    for (int s = 0; s < 4; ++s) { mag[s] = expf(mag[s] - mx); se += mag[s]; }
    float inv = 4.0f / se;                 // RATIO / sum
    float mr = 0.f, mi = 0.f;
    #pragma unroll
    for (int r = 0; r < 4; ++r) { mr = fmaf(pm[r].x, mag[r], mr); mi = fmaf(pm[r].y, mag[r], mi); }
    p1[(((size_t)b * T1n + t1) * CIN + c) * F1n + 4 * f0] = make_float2(mr * inv, mi * inv);
}

// ---------------- complex batch-norm stats -> per-batch affine ------------------
__global__ __launch_bounds__(256)
void cbn_kernel(const float2* __restrict__ p0, const float2* __restrict__ p1,
                const float* __restrict__ gamma, const float* __restrict__ beta,
                float4* __restrict__ bn) {
    int head = blockIdx.x >> 6;
    int b    = blockIdx.x & 63;
    int Nel  = head ? (T1n * CIN * F1n) : (T0n * CIN * F0n);
    const float2* base = head ? (p1 + (size_t)b * (T1n * CIN * F1n))
                              : (p0 + (size_t)b * (T0n * CIN * F0n));
    float sr = 0.f, si = 0.f, s2 = 0.f;
    for (int i = threadIdx.x; i < Nel; i += 256) {
        float2 v = base[i];
        sr += v.x; si += v.y;
        s2 = fmaf(v.x, v.x, s2); s2 = fmaf(v.y, v.y, s2);
    }
    __shared__ float red[3][256];
    red[0][threadIdx.x] = sr; red[1][threadIdx.x] = si; red[2][threadIdx.x] = s2;
    __syncthreads();
    for (int off = 128; off > 0; off >>= 1) {
        if (threadIdx.x < off) {
            red[0][threadIdx.x] += red[0][threadIdx.x + off];
            red[1][threadIdx.x] += red[1][threadIdx.x + off];
            red[2][threadIdx.x] += red[2][threadIdx.x + off];
        }
        __syncthreads();
    }
    if (threadIdx.x == 0) {
        float invN = 1.f / (float)Nel;
        float mur = red[0][0] * invN, mui = red[1][0] * invN;
        float var = red[2][0] * invN - mur * mur - mui * mui;
        float g = gamma[head * BB + b] * rsqrtf(var + 1e-5f);
        bn[head * BB + b] = make_float4(g, beta[head * BB + b] - mur * g, -mui * g, 0.f);
    }
}

// ---------------- init: irfft twiddle matrix, A-fragment order, split fp16 -----
// W[m][k2]: k2=2f -> scale_f*cos(2*pi*m*f/N); k2=2f+1 -> -scale_f*sin(...)
// W scaled by 2^10; S scaled by 2^5; epilogue multiplies by 2^-15.
// frag idx = ((mtile*KT + kt)*64 + lane)*8 + j ; m = mtile*16+(lane&15),
// k2 = kt*32 + (lane>>4)*8 + j.  sin(0)=0 zeroes DC/Nyquist imag (numpy irfft).
__global__ __launch_bounds__(256)
void init_w_kernel(u16* __restrict__ whi0, u16* __restrict__ wlo0,
                   u16* __restrict__ whi1, u16* __restrict__ wlo1) {
    int idx = blockIdx.x * 256 + threadIdx.x;
    int N, F, KT, id; u16 *dh, *dl;
    if (idx < 6144)              { N = 64;  F = F0n; KT = 3; dh = whi0; dl = wlo0; id = idx; }
    else if (idx < 6144 + 73728) { N = 256; F = F1n; KT = 9; dh = whi1; dl = wlo1; id = idx - 6144; }
    else return;
    int j    = id & 7;
    int lane = (id >> 3) & 63;
    int rest = id >> 9;
    int kt   = rest % KT;
    int mt   = rest / KT;
    int m  = mt * 16 + (lane & 15);
    int k2 = kt * 32 + (lane >> 4) * 8 + j;
    float v = 0.f;
    if (k2 < 2 * F) {
        int f = k2 >> 1;
        double scale = (f == 0 || f == F - 1) ? (1024.0 / N) : (2048.0 / N);
        int u = (m * f) % N;
        double th = 6.283185307179586476925286766559 * (double)u / (double)N;
        v = (float)((k2 & 1) ? (-scale * sin(th)) : (scale * cos(th)));
    }
    _Float16 h = (_Float16)v;
    _Float16 l = (_Float16)(v - (float)h);
    dh[id] = *(u16*)&h;
    dl[id] = *(u16*)&l;
}

// ---------------- init: fk tables repacked [f][o][ci] float2 (fp32) -------------
__global__ __launch_bounds__(256)
void init_fk_kernel(const float* __restrict__ r0, const float* __restrict__ i0,
                    const float* __restrict__ r1, const float* __restrict__ i1,
                    float2* __restrict__ d0, float2* __restrict__ d1) {
    int idx = blockIdx.x * 256 + threadIdx.x;
    const float *r, *im; float2* dst; int id;
    if (idx < F0n * 512)               { r = r0; im = i0; dst = d0; id = idx; }
    else if (idx < (F0n + F1n) * 512)  { r = r1; im = i1; dst = d1; id = idx - F0n * 512; }
    else return;
    int f   = id >> 9;
    int rem = id & 511;
    int o   = rem >> 4;
    int ci  = rem & 15;
    int s = (f * CIN + ci) * CO + o;
    dst[id] = make_float2(r[s], im[s]);
}

// ---------------- init: KS[f][o] = sum_ci fk[f][ci][o] (for CBN-offset fold) ---
__global__ __launch_bounds__(256)
void init_ks_kernel(const float* __restrict__ r0, const float* __restrict__ i0,
                    const float* __restrict__ r1, const float* __restrict__ i1,
                    float2* __restrict__ ks0, float2* __restrict__ ks1) {
    int idx = blockIdx.x * 256 + threadIdx.x;
    const float *r, *im; float2* dst; int id;
    if (idx < F0n * CO)              { r = r0; im = i0; dst = ks0; id = idx; }
    else if (idx < (F0n + F1n) * CO) { r = r1; im = i1; dst = ks1; id = idx - F0n * CO; }
    else return;
    int f = id / CO, o = id % CO;
    float sr = 0.f, si = 0.f;
    for (int ci = 0; ci < CIN; ++ci) {
        sr += r[(f * CIN + ci) * CO + o];
        si += im[(f * CIN + ci) * CO + o];
    }
    dst[id] = make_float2(sr, si);
}

// ---------------- fused einsum(raw p, fp32) + CBN fold + irfft(split-fp16 MFMA)
// grid: B*(TFR+1); frame TFR re-uses spectrum of frame 0 (wrap frame)
// S = s*(p . fk) + cb*KS  (CBN affine folded algebraically; no xbn staging)
template<int N, int F, int TFR, int CH0, int KT, int KPAD>
__global__ __launch_bounds__(256)
void istft_kernel(const float2* __restrict__ p,
                  const u16* __restrict__ whi, const u16* __restrict__ wlo,
                  const float2* __restrict__ fkb, const float2* __restrict__ ks,
                  const float4* __restrict__ bn,
                  const float* __restrict__ pbias, float* __restrict__ out) {
    constexpr int MTW = N / 64;            // M-tiles per wave (1 or 4)
    __shared__ u16 Shi[32][KPAD];          // [o][k2] f16 hi (x32 scale)
    __shared__ u16 Slo[32][KPAD];          // [o][k2] f16 lo (residual)

    int t  = blockIdx.x % (TFR + 1);
    int b  = blockIdx.x / (TFR + 1);
    int tf = (t == TFR) ? 0 : t;
    float4 par = bn[(CH0 ? 1 : 0) * BB + b];   // (s, cb_re, cb_im, -)
    const float2* pbase = p + ((size_t)b * TFR + tf) * CIN * F;

    // einsum (fp32, raw p): S[o][2f]=re*32, S[o][2f+1]=im*32
    for (int i = threadIdx.x; i < F * CO; i += 256) {
        int f = i >> 5, o = i & 31;
        const float4*  kk4  = (const float4*)(fkb + (size_t)i * 16);  // 8x (kr,ki,kr,ki)
        const float2*  prow = pbase + f;                              // + ci*F
        float re = 0.f, im = 0.f;
        #pragma unroll
        for (int q = 0; q < 8; ++q) {
            float4 kk = kk4[q];
            float2 v0 = prow[(2 * q) * F];
            float2 v1 = prow[(2 * q + 1) * F];
            re = fmaf(v0.x, kk.x, re); re = fmaf(-v0.y, kk.y, re);
            im = fmaf(v0.x, kk.y, im); im = fmaf(v0.y, kk.x, im);
            re = fmaf(v1.x, kk.z, re); re = fmaf(-v1.y, kk.w, re);
            im = fmaf(v1.x, kk.w, im); im = fmaf(v1.y, kk.z, im);
        }
        // affine fold: S = s*Sraw + cb*KS ; then x32 scale
        float2 k2v = ks[i];
        float res = fmaf(par.x, re, fmaf(par.y, k2v.x, -par.z * k2v.y)) * 32.f;
        float ims = fmaf(par.x, im, fmaf(par.y, k2v.y,  par.z * k2v.x)) * 32.f;
        _Float16 rh = (_Float16)res; _Float16 rl = (_Float16)(res - (float)rh);
        _Float16 ih = (_Float16)ims; _Float16 il = (_Float16)(ims - (float)ih);
        ((uint32*)&Shi[o][0])[f] = ((uint32)(*(u16*)&ih) << 16) | (uint32)(*(u16*)&rh);
        ((uint32*)&Slo[o][0])[f] = ((uint32)(*(u16*)&il) << 16) | (uint32)(*(u16*)&rl);
    }
    // zero-pad K region [F, KT*16) dwords in both arrays
    for (int i = threadIdx.x; i < 32 * (KT * 16 - F); i += 256) {
        constexpr int cols = KT * 16 - F;
        int o = i / cols, j = i - o * cols;
        ((uint32*)&Shi[o][0])[F + j] = 0;
        ((uint32*)&Slo[o][0])[F + j] = 0;
    }
    __syncthreads();

    // MFMA: out[k][ch] = sum_k2 W[k][k2]*S[k2][ch],  W*S ~ Wh*Sh + Wh*Sl + Wl*Sh
    int lane = threadIdx.x & 63, wave = threadIdx.x >> 6;
    int col = lane & 15, quad = lane >> 4;
    f32x4 accv[MTW][2];
    #pragma unroll
    for (int mt = 0; mt < MTW; ++mt)
        #pragma unroll
        for (int nt = 0; nt < 2; ++nt) {
            f32x4 z = {0.f, 0.f, 0.f, 0.f};
            accv[mt][nt] = z;
        }
    for (int kt = 0; kt < KT; ++kt) {
        half8 bh0 = *(const half8*)&Shi[col][kt * 32 + quad * 8];
        half8 bh1 = *(const half8*)&Shi[16 + col][kt * 32 + quad * 8];
        half8 bl0 = *(const half8*)&Slo[col][kt * 32 + quad * 8];
        half8 bl1 = *(const half8*)&Slo[16 + col][kt * 32 + quad * 8];
        #pragma unroll
        for (int mt = 0; mt < MTW; ++mt) {
            int mtile = wave * MTW + mt;
            half8 ah = ((const half8*)whi)[(mtile * KT + kt) * 64 + lane];
            half8 al = ((const half8*)wlo)[(mtile * KT + kt) * 64 + lane];
            accv[mt][0] = __builtin_amdgcn_mfma_f32_16x16x32_f16(ah, bh0, accv[mt][0], 0, 0, 0);
            accv[mt][0] = __builtin_amdgcn_mfma_f32_16x16x32_f16(ah, bl0, accv[mt][0], 0, 0, 0);
            accv[mt][0] = __builtin_amdgcn_mfma_f32_16x16x32_f16(al, bh0, accv[mt][0], 0, 0, 0);
            accv[mt][1] = __builtin_amdgcn_mfma_f32_16x16x32_f16(ah, bh1, accv[mt][1], 0, 0, 0);
            accv[mt][1] = __builtin_amdgcn_mfma_f32_16x16x32_f16(ah, bl1, accv[mt][1], 0, 0, 0);
            accv[mt][1] = __builtin_amdgcn_mfma_f32_16x16x32_f16(al, bh1, accv[mt][1], 0, 0, 0);
        }
    }
    // epilogue: row = quad*4+reg (4 consecutive l), col = ch within ntile
    constexpr float UNSCALE = 1.0f / 32768.0f;   // 2^-15 (W*2^10, S*2^5)
    size_t bb = (size_t)b * TCO;
    #pragma unroll
    for (int mt = 0; mt < MTW; ++mt) {
        int l0 = t * N + (wave * MTW + mt) * 16 + quad * 4 - N / 2;
        if ((unsigned)l0 < LL) {
            #pragma unroll
            for (int nt = 0; nt < 2; ++nt) {
                int ch = CH0 + nt * 16 + col;
                float pb = pbias[ch];
                f32x4 a = accv[mt][nt];
                float4 v;
                v.x = fmaxf(fmaf(a[0], UNSCALE, pb), 0.f);
                v.y = fmaxf(fmaf(a[1], UNSCALE, pb), 0.f);
                v.z = fmaxf(fmaf(a[2], UNSCALE, pb), 0.f);
                v.w = fmaxf(fmaf(a[3], UNSCALE, pb), 0.f);
                *(float4*)(out + (bb + ch) * LL + l0) = v;
            }
        }
    }
}

extern "C" void kernel_launch(void* const* d_in, const int* in_sizes, int n_in,
                              void* d_out, int out_size, void* d_ws, size_t ws_size,
                              hipStream_t stream) {
    const float* x     = (const float*)d_in[0];
    const float* gam   = (const float*)d_in[1];
    const float* bet   = (const float*)d_in[2];
    const float* mkr   = (const float*)d_in[3];
    const float* mki   = (const float*)d_in[4];
    const float* mbr   = (const float*)d_in[5];
    const float* mbi   = (const float*)d_in[6];
    const float* fk0r  = (const float*)d_in[7];
    const float* fk0i  = (const float*)d_in[8];
    const float* fk1r  = (const float*)d_in[9];
    const float* fk1i  = (const float*)d_in[10];
    const float* pbias = (const float*)d_in[11];
    float* out = (float*)d_out;

    float2* p0   = (float2*)d_ws;                                   // 34.6 MB
    float2* p1   = p0 + (size_t)BB * T0n * CIN * F0n;               // 33.8 MB
    float4* bnp  = (float4*)(p1 + (size_t)BB * T1n * CIN * F1n);    // 2 KB
    u16*    whi0 = (u16*)(bnp + 2 * BB);                            // 12 KB
    u16*    wlo0 = whi0 + 6144;
    u16*    whi1 = wlo0 + 6144;                                     // 144 KB
    u16*    wlo1 = whi1 + 73728;
    float2* fkb0 = (float2*)(wlo1 + 73728);                         // 132 KB
    float2* fkb1 = fkb0 + F0n * 512;                                // 516 KB
    float2* ks0  = fkb1 + F1n * 512;                                // 8.25 KB
    float2* ks1  = ks0 + F0n * CO;                                  // 32.25 KB

    init_w_kernel<<<(6144 + 73728 + 255) / 256, 256, 0, stream>>>(whi0, wlo0, whi1, wlo1);
    init_fk_kernel<<<((F0n + F1n) * 512 + 255) / 256, 256, 0, stream>>>(
        fk0r, fk0i, fk1r, fk1i, fkb0, fkb1);
    init_ks_kernel<<<((F0n + F1n) * CO + 255) / 256, 256, 0, stream>>>(
        fk0r, fk0i, fk1r, fk1i, ks0, ks1);
    stft_kernel<64, 33, 8, 128><<<BB * CIN * 16, 256, 0, stream>>>(x, p0);
    stft_kernel<256, 129, 2, 32><<<BB * CIN * 16, 256, 0, stream>>>(x, p1);
    merge_kernel<<<(BB * T1n * CIN * F0n) / 256, 256, 0, stream>>>(p0, p1, mkr, mki, mbr, mbi);
    cbn_kernel<<<128, 256, 0, stream>>>(p0, p1, gam, bet, bnp);
    istft_kernel<64, 33, 128, 0, 3, 104><<<BB * (T0n + 1), 256, 0, stream>>>(
        p0, whi0, wlo0, fkb0, ks0, bnp, pbias, out);
    istft_kernel<256, 129, 32, 32, 9, 296><<<BB * (T1n + 1), 256, 0, stream>>>(
        p1, whi1, wlo1, fkb1, ks1, bnp, pbias, out);
}